// Round 5
// baseline (2672.771 us; speedup 1.0000x reference)
//
#include <hip/hip_runtime.h>
#include <hip/hip_bf16.h>

typedef __attribute__((ext_vector_type(8))) __bf16 bf16x8;
typedef __attribute__((ext_vector_type(4))) float f32x4;

#define MFMA(a,b,c) __builtin_amdgcn_mfma_f32_16x16x32_bf16((a),(b),(c),0,0,0)

__device__ __forceinline__ bf16x8 cvt8(float4 a, float4 b){
  bf16x8 r;
  r[0]=(__bf16)a.x; r[1]=(__bf16)a.y; r[2]=(__bf16)a.z; r[3]=(__bf16)a.w;
  r[4]=(__bf16)b.x; r[5]=(__bf16)b.y; r[6]=(__bf16)b.z; r[7]=(__bf16)b.w;
  return r;
}

// Wp: old layout (B-operand), mats {0:sg,1:dg,2:eg,3:su}; frag=kt*4+nt;
//     lane holds W[kt*32+(l>>4)*8+j][nt*16+(l&15)]
// Wq: transposed layout (A-operand), mats {0:eg,1:sg,2:dg,3:du}; frag=mt*2+kh;
//     lane holds W[kh*32+(l>>4)*8+j][mt*16+(l&15)]  (= W^T[mt*16+m][k])
__global__ void wcvt(const float* __restrict__ W_sg, const float* __restrict__ W_dg,
                     const float* __restrict__ W_eg, const float* __restrict__ W_su,
                     const float* __restrict__ W_du,
                     bf16x8* __restrict__ Wp, bf16x8* __restrict__ Wq){
  int tid = blockIdx.x*256 + threadIdx.x;
  if (tid >= 4096) return;
  int lane = tid & 63, g = lane>>4, c = lane&15;
  if (tid < 2048){
    int frag = (tid>>6)&7, m = tid>>9;
    const float* Ws[4] = {W_sg, W_dg, W_eg, W_su};
    const float* W = Ws[m];
    int kt = frag>>2, nt = frag&3;
    bf16x8 v;
    #pragma unroll
    for (int j=0;j<8;j++) v[j] = (__bf16)W[(kt*32+g*8+j)*64 + nt*16 + c];
    Wp[tid] = v;
  } else {
    int t2 = tid - 2048;
    int frag = (t2>>6)&7, m = t2>>9;
    const float* Ws[4] = {W_eg, W_sg, W_dg, W_du};
    const float* W = Ws[m];
    int mt = frag>>1, kh = frag&1;
    bf16x8 v;
    #pragma unroll
    for (int j=0;j<8;j++) v[j] = (__bf16)W[(kh*32+g*8+j)*64 + mt*16 + c];
    Wq[t2] = v;
  }
}

// A_src = nf @ W_su + b_su  (only node transform still materialized)
__global__ __launch_bounds__(256) void node_xform(
    const float* __restrict__ nf, const bf16x8* __restrict__ Wp,
    const float* __restrict__ b_su, float* __restrict__ A_src, int ntiles)
{
  int lane = threadIdx.x & 63;
  int gw = blockIdx.x*4 + (threadIdx.x>>6);
  if (gw >= ntiles) return;
  int g = lane>>4, c = lane&15;
  long base = (long)gw*16;
  const float* rp = nf + (base + c)*64 + g*8;
  float4 a0 = *(const float4*)rp,      a1 = *(const float4*)(rp+4);
  float4 a2 = *(const float4*)(rp+32), a3 = *(const float4*)(rp+36);
  bf16x8 A0 = cvt8(a0,a1), A1 = cvt8(a2,a3);
  #pragma unroll
  for (int nt=0;nt<4;nt++){
    f32x4 acc = {0.f,0.f,0.f,0.f};
    acc = MFMA(A0, Wp[(3*8+nt)*64+lane],   acc);
    acc = MFMA(A1, Wp[(3*8+4+nt)*64+lane], acc);
    int col = c + nt*16;
    float bb = b_su[col];
    #pragma unroll
    for (int e=0;e<4;e++) A_src[(base+4*g+e)*64 + col] = acc[e] + bb;
  }
}

// ---- CSR build on dst ----
__global__ void hist_k(const int* __restrict__ dst, int* __restrict__ cnt, int E){
  int i = blockIdx.x*256 + threadIdx.x, st = gridDim.x*256;
  for (; i<E; i+=st) atomicAdd(&cnt[dst[i]], 1);
}

__global__ __launch_bounds__(1024) void scan_k(const int* __restrict__ cnt,
                                               int* __restrict__ row, int Nn){
  __shared__ int part[1024];
  int t = threadIdx.x;
  int C = (Nn + 1023) >> 10;
  int lo = t*C;
  int hi = lo + C; if (hi > Nn) hi = Nn;
  int s = 0;
  for (int i=lo; i<hi; i++) s += cnt[i];
  part[t] = s;
  __syncthreads();
  for (int off=1; off<1024; off<<=1){
    int v = part[t];
    int u = (t>=off) ? part[t-off] : 0;
    __syncthreads();
    part[t] = v + u;
    __syncthreads();
  }
  int excl = (t==0) ? 0 : part[t-1];
  for (int i=lo; i<hi; i++){ row[i] = excl; excl += cnt[i]; }
}

// fill: rowp holds segment starts; atomic cursor destroys it (nothing else reads it)
__global__ void fill_k(const int* __restrict__ src, const int* __restrict__ dst,
                       int* __restrict__ rowp, int2* __restrict__ pairs,
                       int* __restrict__ dsts, int E){
  int i = blockIdx.x*256 + threadIdx.x, st = gridDim.x*256;
  for (; i<E; i+=st){
    int d = dst[i];
    int pos = atomicAdd(&rowp[d], 1);
    pairs[pos] = make_int2(i, src[i]);
    dsts[pos] = d;
  }
}

// ---- pass1b: edge-major, transposed MFMA (lane owns one edge),
// segmented shfl-scan over sorted dst, one atomic per segment tail.
__global__ __launch_bounds__(256) void pass1b(
    const float* __restrict__ ef, const float* __restrict__ nf,
    const int2* __restrict__ pairs, const int* __restrict__ dsts,
    const float* __restrict__ b_sg, const float* __restrict__ b_dg,
    const float* __restrict__ b_eg, const float* __restrict__ b_du,
    const bf16x8* __restrict__ Wq,
    float* __restrict__ ss, float* __restrict__ ssh,
    float* __restrict__ est, int ntiles)
{
  __shared__ bf16x8 wl[32*64];
  {
    int t = threadIdx.x;
    #pragma unroll
    for (int i=0;i<8;i++) wl[i*256+t] = Wq[i*256+t];
  }
  __syncthreads();
  int lane = threadIdx.x & 63, g = lane>>4, c = lane&15;
  int gw = blockIdx.x*4 + (threadIdx.x>>6);
  int nw = gridDim.x*4;
  // per-lane feature set: f(mt,e) = mt*16 + 4g + e
  float bm[4][4], bd[4][4], es1[4][4], es2[4][4];
  #pragma unroll
  for (int mt=0;mt<4;mt++)
    #pragma unroll
    for (int e=0;e<4;e++){
      int f = mt*16 + 4*g + e;
      bm[mt][e] = b_sg[f] + b_dg[f] + b_eg[f];
      bd[mt][e] = b_du[f];
      es1[mt][e] = 0.f; es2[mt][e] = 0.f;
    }

  for (int tt=gw; tt<ntiles; tt+=nw){
    int base = tt*16;
    int2 pr = pairs[base + c];
    int d   = dsts[base + c];
    const float* rpe = ef + (long)pr.x*64 + g*8;
    const float* rpn = nf + (long)pr.y*64 + g*8;
    const float* rpd = nf + (long)d*64    + g*8;
    float4 e0=*(const float4*)rpe,      e1=*(const float4*)(rpe+4);
    float4 e2=*(const float4*)(rpe+32), e3=*(const float4*)(rpe+36);
    float4 s0=*(const float4*)rpn,      s1=*(const float4*)(rpn+4);
    float4 s2=*(const float4*)(rpn+32), s3=*(const float4*)(rpn+36);
    float4 d0=*(const float4*)rpd,      d1=*(const float4*)(rpd+4);
    float4 d2=*(const float4*)(rpd+32), d3=*(const float4*)(rpd+36);
    bf16x8 BE0=cvt8(e0,e1), BE1=cvt8(e2,e3);
    bf16x8 BS0=cvt8(s0,s1), BS1=cvt8(s2,s3);
    bf16x8 BD0=cvt8(d0,d1), BD1=cvt8(d2,d3);
    // segment flags (dst sorted within CSR order)
    int du1=__shfl_up(d,1,16), du2=__shfl_up(d,2,16),
        du4=__shfl_up(d,4,16), du8=__shfl_up(d,8,16);
    bool ok1=(c>=1)&&(du1==d), ok2=(c>=2)&&(du2==d),
         ok4=(c>=4)&&(du4==d), ok8=(c>=8)&&(du8==d);
    int dn = __shfl_down(d,1,16);
    bool tail = (c==15) || (dn != d);
    long drow = (long)d*64;
    #pragma unroll
    for (int mt=0;mt<4;mt++){
      f32x4 am = {0.f,0.f,0.f,0.f}, ab = {0.f,0.f,0.f,0.f};
      am = MFMA(wl[((0*4+mt)*2+0)*64+lane], BE0, am);
      am = MFMA(wl[((0*4+mt)*2+1)*64+lane], BE1, am);
      am = MFMA(wl[((1*4+mt)*2+0)*64+lane], BS0, am);
      am = MFMA(wl[((1*4+mt)*2+1)*64+lane], BS1, am);
      am = MFMA(wl[((2*4+mt)*2+0)*64+lane], BD0, am);
      am = MFMA(wl[((2*4+mt)*2+1)*64+lane], BD1, am);
      ab = MFMA(wl[((3*4+mt)*2+0)*64+lane], BS0, ab);
      ab = MFMA(wl[((3*4+mt)*2+1)*64+lane], BS1, ab);
      #pragma unroll
      for (int e=0;e<4;e++){
        float mv = am[e] + bm[mt][e];
        float sg = 1.f/(1.f+__expf(-mv));
        float bh = (ab[e] + bd[mt][e])*sg;
        es1[mt][e] += mv; es2[mt][e] += mv*mv;
        // segmented inclusive scan across c (16 lanes)
        float u;
        u=__shfl_up(sg,1,16); if(ok1) sg+=u;
        u=__shfl_up(bh,1,16); if(ok1) bh+=u;
        u=__shfl_up(sg,2,16); if(ok2) sg+=u;
        u=__shfl_up(bh,2,16); if(ok2) bh+=u;
        u=__shfl_up(sg,4,16); if(ok4) sg+=u;
        u=__shfl_up(bh,4,16); if(ok4) bh+=u;
        u=__shfl_up(sg,8,16); if(ok8) sg+=u;
        u=__shfl_up(bh,8,16); if(ok8) bh+=u;
        if (tail){
          int f = mt*16 + 4*g + e;
          atomicAdd(&ss[drow+f],  sg);
          atomicAdd(&ssh[drow+f], bh);
        }
      }
    }
  }
  // edge BN stats flush
  #pragma unroll
  for (int mt=0;mt<4;mt++)
    #pragma unroll
    for (int e=0;e<4;e++){
      float a = es1[mt][e], b = es2[mt][e];
      a+=__shfl_xor(a,1,16); a+=__shfl_xor(a,2,16); a+=__shfl_xor(a,4,16); a+=__shfl_xor(a,8,16);
      b+=__shfl_xor(b,1,16); b+=__shfl_xor(b,2,16); b+=__shfl_xor(b,4,16); b+=__shfl_xor(b,8,16);
      if (c==0){
        int f = mt*16 + 4*g + e;
        atomicAdd(&est[f],    a);
        atomicAdd(&est[64+f], b);
      }
    }
}

// x_pre = A_src + ssh/(ss+1e-6) written in place; node BN stats
__global__ __launch_bounds__(256) void node_stats(
    float* __restrict__ A_src, const float* __restrict__ ssh,
    const float* __restrict__ ss, float* __restrict__ nst, int Nn)
{
  int tid = blockIdx.x*blockDim.x + threadIdx.x;
  int col = tid & 63;
  int row0 = tid >> 6;
  int rstride = (gridDim.x*blockDim.x) >> 6;
  float s=0.f, q=0.f;
  for (int r=row0; r<Nn; r+=rstride){
    long i = (long)r*64 + col;
    float x = A_src[i] + ssh[i]/(ss[i]+1e-6f);
    A_src[i] = x;
    s += x; q += x*x;
  }
  atomicAdd(&nst[col], s); atomicAdd(&nst[64+col], q);
}

// x = nf + silu(bn(x_pre))
__global__ __launch_bounds__(256) void node_final(
    const float* __restrict__ nf, const float* __restrict__ xpre,
    const float* __restrict__ nst, const float* __restrict__ gam,
    const float* __restrict__ bet, float* __restrict__ xo, int Nn)
{
  long tid = blockIdx.x*blockDim.x + threadIdx.x;
  long stride = (long)gridDim.x*blockDim.x;
  int col = (int)(tid & 63);
  float invN = 1.f/(float)Nn;
  float mu = nst[col]*invN;
  float var = nst[64+col]*invN - mu*mu;
  float rs = rsqrtf(var + 1e-5f);
  float aa = gam[col]*rs;
  float bb = bet[col] - mu*aa;
  long total = (long)Nn*64;
  for (long i=tid; i<total; i+=stride){
    float z = xpre[i]*aa + bb;
    xo[i] = nf[i] + z/(1.f+__expf(-z));
  }
}

// y = ef + silu(bn(m)); m recomputed from nf gathers + MFMA (no e_src/e_dst arrays)
__global__ __launch_bounds__(256) void edge_pass2(
    const float* __restrict__ ef, const float* __restrict__ nf,
    const int* __restrict__ src, const int* __restrict__ dst,
    const float* __restrict__ b_sg, const float* __restrict__ b_dg,
    const float* __restrict__ b_eg, const bf16x8* __restrict__ Wp,
    const float* __restrict__ est, const float* __restrict__ gam,
    const float* __restrict__ bet, float* __restrict__ y, float invE, int ntiles)
{
  __shared__ bf16x8 wl[24*64];   // 0-7 eg, 8-15 sg, 16-23 dg
  {
    int t = threadIdx.x;
    #pragma unroll
    for (int i=0;i<6;i++){
      int idx = i*256 + t;
      int fr = idx>>6, ln = idx&63;
      int sf = (fr<8) ? (2*8+fr) : ((fr<16) ? (fr-8) : (1*8+fr-16));
      wl[idx] = Wp[sf*64+ln];
    }
  }
  __syncthreads();
  int lane = threadIdx.x & 63, g = lane>>4, c = lane&15;
  int gw = blockIdx.x*4 + (threadIdx.x>>6);
  int nw = gridDim.x*4;
  float bias[4], aa[4], bb2[4];
  #pragma unroll
  for (int nt=0;nt<4;nt++){
    int col = c + nt*16;
    bias[nt] = b_sg[col] + b_dg[col] + b_eg[col];
    float mu = est[col]*invE;
    float var = est[64+col]*invE - mu*mu;
    float rs = rsqrtf(var + 1e-5f);
    float ga = gam[col]*rs;
    aa[nt] = ga; bb2[nt] = bet[col] - mu*ga;
  }
  for (int tt=gw; tt<ntiles; tt+=nw){
    long base = (long)tt*16;
    const float* rpe = ef + (base+c)*64 + g*8;
    float4 a0=*(const float4*)rpe,      a1=*(const float4*)(rpe+4);
    float4 a2=*(const float4*)(rpe+32), a3=*(const float4*)(rpe+36);
    bf16x8 AE0=cvt8(a0,a1), AE1=cvt8(a2,a3);
    int s_c = src[base+c], d_c = dst[base+c];
    const float* rps = nf + (long)s_c*64 + g*8;
    const float* rpd = nf + (long)d_c*64 + g*8;
    float4 s0=*(const float4*)rps,      s1=*(const float4*)(rps+4);
    float4 s2=*(const float4*)(rps+32), s3=*(const float4*)(rps+36);
    float4 d0=*(const float4*)rpd,      d1=*(const float4*)(rpd+4);
    float4 d2=*(const float4*)(rpd+32), d3=*(const float4*)(rpd+36);
    bf16x8 AS0=cvt8(s0,s1), AS1=cvt8(s2,s3);
    bf16x8 AD0=cvt8(d0,d1), AD1=cvt8(d2,d3);
    #pragma unroll
    for (int nt=0;nt<4;nt++){
      f32x4 acc = {0.f,0.f,0.f,0.f};
      acc = MFMA(AE0, wl[(   nt)*64+lane], acc);
      acc = MFMA(AE1, wl[( 4+nt)*64+lane], acc);
      acc = MFMA(AS0, wl[( 8+nt)*64+lane], acc);
      acc = MFMA(AS1, wl[(12+nt)*64+lane], acc);
      acc = MFMA(AD0, wl[(16+nt)*64+lane], acc);
      acc = MFMA(AD1, wl[(20+nt)*64+lane], acc);
      int col = c + nt*16;
      #pragma unroll
      for (int e=0;e<4;e++){
        long er = base + 4*g + e;
        float mv = acc[e] + bias[nt];
        float z = mv*aa[nt] + bb2[nt];
        float sil = z/(1.f+__expf(-z));
        y[er*64+col] = ef[er*64+col] + sil;
      }
    }
  }
}

extern "C" void kernel_launch(void* const* d_in, const int* in_sizes, int n_in,
                              void* d_out, int out_size, void* d_ws, size_t ws_size,
                              hipStream_t stream){
  const float* nf  = (const float*)d_in[0];
  const float* ef  = (const float*)d_in[1];
  const int*   src = (const int*)d_in[2];
  const int*   dst = (const int*)d_in[3];
  const float* W_sg=(const float*)d_in[4];  const float* b_sg=(const float*)d_in[5];
  const float* W_dg=(const float*)d_in[6];  const float* b_dg=(const float*)d_in[7];
  const float* W_eg=(const float*)d_in[8];  const float* b_eg=(const float*)d_in[9];
  const float* W_su=(const float*)d_in[10]; const float* b_su=(const float*)d_in[11];
  const float* W_du=(const float*)d_in[12]; const float* b_du=(const float*)d_in[13];
  const float* gn=(const float*)d_in[14];   const float* btn=(const float*)d_in[15];
  const float* ge=(const float*)d_in[16];   const float* bte=(const float*)d_in[17];

  int Nn = in_sizes[0]/64;
  int Ee = in_sizes[2];
  size_t Nf = (size_t)Nn*64;

  float* ws    = (float*)d_ws;
  float* A_src = ws;                         // Nf (becomes x_pre)
  float* ss    = ws + Nf;                    // Nf
  float* ssh   = ws + 2*Nf;                  // Nf
  int*   cnt   = (int*)(ws + 3*Nf);          // Nn
  float* est   = (float*)(cnt + Nn);         // 128
  float* nst   = est + 128;                  // 128
  int*   rowp  = (int*)(nst + 128);          // Nn (+pad to mult of 4)
  size_t off   = 3*Nf + (size_t)Nn + 256 + (((size_t)Nn + 3) & ~(size_t)3);
  int2*  pairs = (int2*)(ws + off);          // Ee int2
  int*   dsts  = (int*)(pairs + Ee);         // Ee
  size_t off2  = off + 3*(size_t)Ee;
  off2 = (off2 + 3) & ~(size_t)3;
  bf16x8* Wp   = (bf16x8*)(ws + off2);       // 2048 frags
  bf16x8* Wq   = Wp + 2048;                  // 2048 frags

  float* xo = (float*)d_out;
  float* yo = xo + Nf;

  // zero: ss, ssh, cnt, est, nst (contiguous)
  hipMemsetAsync(ss, 0, (2*Nf + (size_t)Nn + 256)*sizeof(float), stream);

  wcvt<<<16,256,0,stream>>>(W_sg,W_dg,W_eg,W_su,W_du,Wp,Wq);

  int ntn = Nn/16;
  node_xform<<<(ntn+3)/4,256,0,stream>>>(nf,Wp,b_su,A_src,ntn);
  hist_k<<<2048,256,0,stream>>>(dst,cnt,Ee);
  scan_k<<<1,1024,0,stream>>>(cnt,rowp,Nn);
  fill_k<<<2048,256,0,stream>>>(src,dst,rowp,pairs,dsts,Ee);
  int nte = Ee/16;
  pass1b<<<4096,256,0,stream>>>(ef,nf,pairs,dsts,b_sg,b_dg,b_eg,b_du,Wq,
                                ss,ssh,est,nte);
  node_stats<<<512,256,0,stream>>>(A_src,ssh,ss,nst,Nn);
  node_final<<<2048,256,0,stream>>>(nf,A_src,nst,gn,btn,xo,Nn);
  edge_pass2<<<2048,256,0,stream>>>(ef,nf,src,dst,b_sg,b_dg,b_eg,Wp,est,ge,bte,yo,
                                    1.f/(float)Ee,nte);
}

// Round 6
// 1042.040 us; speedup vs baseline: 2.5649x; 2.5649x over previous
//
#include <hip/hip_runtime.h>
#include <hip/hip_bf16.h>

typedef __attribute__((ext_vector_type(8))) __bf16 bf16x8;
typedef __attribute__((ext_vector_type(4))) float f32x4;

#define MFMA(a,b,c) __builtin_amdgcn_mfma_f32_16x16x32_bf16((a),(b),(c),0,0,0)

__device__ __forceinline__ bf16x8 cvt8(float4 a, float4 b){
  bf16x8 r;
  r[0]=(__bf16)a.x; r[1]=(__bf16)a.y; r[2]=(__bf16)a.z; r[3]=(__bf16)a.w;
  r[4]=(__bf16)b.x; r[5]=(__bf16)b.y; r[6]=(__bf16)b.z; r[7]=(__bf16)b.w;
  return r;
}

// Pack 5 weight matrices [64][64] f32 into bf16 MFMA B-fragments.
// mats 0:sg 1:dg 2:eg 3:su 4:du; Wp[(m*8+kt*4+nt)*64+lane]:
// lane holds W[k=kt*32+(l>>4)*8+j][n=nt*16+(l&15)]
__global__ void wcvt(const float* __restrict__ W0, const float* __restrict__ W1,
                     const float* __restrict__ W2, const float* __restrict__ W3,
                     const float* __restrict__ W4, bf16x8* __restrict__ Wp){
  int tid = blockIdx.x*256 + threadIdx.x;
  if (tid >= 5*8*64) return;
  int lane = tid & 63, frag = (tid>>6)&7, m = tid>>9;
  const float* Ws[5] = {W0,W1,W2,W3,W4};
  const float* W = Ws[m];
  int kt = frag>>2, nt = frag&3, g = lane>>4, c = lane&15;
  bf16x8 v;
  #pragma unroll
  for (int j=0;j<8;j++) v[j] = (__bf16)W[(kt*32+g*8+j)*64 + nt*16 + c];
  Wp[tid] = v;
}

// 2 node transforms: A_src = nf@W_su+b_su, Bh = nf@W_du+b_du
__global__ __launch_bounds__(256) void node_xform(
    const float* __restrict__ nf, const bf16x8* __restrict__ Wp,
    const float* __restrict__ b_su, const float* __restrict__ b_du,
    float* __restrict__ A_src, float* __restrict__ Bh, int ntiles)
{
  int lane = threadIdx.x & 63;
  int gw = blockIdx.x*4 + (threadIdx.x>>6);
  if (gw >= ntiles) return;
  int g = lane>>4, c = lane&15;
  long base = (long)gw*16;
  const float* rp = nf + (base + c)*64 + g*8;
  float4 a0 = *(const float4*)rp,      a1 = *(const float4*)(rp+4);
  float4 a2 = *(const float4*)(rp+32), a3 = *(const float4*)(rp+36);
  bf16x8 A0 = cvt8(a0,a1), A1 = cvt8(a2,a3);
  const float* biases[2] = {b_su,b_du};
  float* outs[2] = {A_src,Bh};
  const int mats[2] = {3,4};
  #pragma unroll
  for (int i=0;i<2;i++){
    #pragma unroll
    for (int nt=0;nt<4;nt++){
      f32x4 acc = {0.f,0.f,0.f,0.f};
      acc = MFMA(A0, Wp[(mats[i]*8+nt)*64+lane],   acc);
      acc = MFMA(A1, Wp[(mats[i]*8+4+nt)*64+lane], acc);
      int col = c + nt*16;
      float bb = biases[i][col];
      #pragma unroll
      for (int e=0;e<4;e++) outs[i][(base+4*g+e)*64 + col] = acc[e] + bb;
    }
  }
}

// ---- CSR build on dst ----
__global__ void hist_k(const int* __restrict__ dst, int* __restrict__ cnt, int E){
  int i = blockIdx.x*256 + threadIdx.x, st = gridDim.x*256;
  for (; i<E; i+=st) atomicAdd(&cnt[dst[i]], 1);
}

__global__ __launch_bounds__(1024) void scan_k(const int* __restrict__ cnt,
                                               int* __restrict__ row, int Nn){
  __shared__ int part[1024];
  int t = threadIdx.x;
  int C = (Nn + 1023) >> 10;
  int lo = t*C;
  int hi = lo + C; if (hi > Nn) hi = Nn;
  int s = 0;
  for (int i=lo; i<hi; i++) s += cnt[i];
  part[t] = s;
  __syncthreads();
  for (int off=1; off<1024; off<<=1){
    int v = part[t];
    int u = (t>=off) ? part[t-off] : 0;
    __syncthreads();
    part[t] = v + u;
    __syncthreads();
  }
  int excl = (t==0) ? 0 : part[t-1];
  for (int i=lo; i<hi; i++){ row[i] = excl; excl += cnt[i]; }
  if (t==1023) row[Nn] = excl;
}

// fill CSR-position records: {edge_id, src, dst, 0}; cnt2 is the cursor (rowp kept clean)
__global__ void fill_k(const int* __restrict__ src, const int* __restrict__ dst,
                       const int* __restrict__ rowp, int* __restrict__ cnt2,
                       int4* __restrict__ pairs, int E){
  int i = blockIdx.x*256 + threadIdx.x, st = gridDim.x*256;
  for (; i<E; i+=st){
    int d = dst[i];
    int pos = rowp[d] + atomicAdd(&cnt2[d], 1);
    pairs[pos] = make_int4(i, src[i], d, 0);
  }
}

// ---- phaseA: edge-major over CSR positions. m = ef@W_eg + nf[src]@W_sg
// + nf[dst]@W_dg + biases, stored bf16 in CSR order. No atomics, no shfl.
__global__ __launch_bounds__(256) void phaseA(
    const float* __restrict__ ef, const float* __restrict__ nf,
    const int4* __restrict__ pairs,
    const float* __restrict__ b_sg, const float* __restrict__ b_dg,
    const float* __restrict__ b_eg,
    const bf16x8* __restrict__ Wp,
    __bf16* __restrict__ m16, int ntiles)
{
  __shared__ bf16x8 wl[24*64];   // 0-7: eg, 8-15: sg, 16-23: dg
  {
    int t = threadIdx.x;
    #pragma unroll
    for (int i=0;i<6;i++){
      int idx = i*256 + t, fr = idx>>6, ln = idx&63;
      int mat = (fr<8) ? 2 : ((fr<16) ? 0 : 1);
      wl[idx] = Wp[(mat*8 + (fr&7))*64 + ln];
    }
  }
  __syncthreads();
  int lane = threadIdx.x & 63, g = lane>>4, c = lane&15;
  int gw = blockIdx.x*4 + (threadIdx.x>>6);
  int nw = gridDim.x*4;
  float bias[4];
  #pragma unroll
  for (int nt=0;nt<4;nt++){
    int col = c + 16*nt;
    bias[nt] = b_sg[col] + b_dg[col] + b_eg[col];
  }
  for (int tt=gw; tt<ntiles; tt+=nw){
    long base = (long)tt*16;
    int4 pr = pairs[base + c];
    const float* rpe = ef + (long)pr.x*64 + g*8;
    const float* rps = nf + (long)pr.y*64 + g*8;
    const float* rpd = nf + (long)pr.z*64 + g*8;
    float4 e0=*(const float4*)rpe,      e1=*(const float4*)(rpe+4);
    float4 e2=*(const float4*)(rpe+32), e3=*(const float4*)(rpe+36);
    float4 s0=*(const float4*)rps,      s1=*(const float4*)(rps+4);
    float4 s2=*(const float4*)(rps+32), s3=*(const float4*)(rps+36);
    float4 d0=*(const float4*)rpd,      d1=*(const float4*)(rpd+4);
    float4 d2=*(const float4*)(rpd+32), d3=*(const float4*)(rpd+36);
    bf16x8 AE0=cvt8(e0,e1), AE1=cvt8(e2,e3);
    bf16x8 AS0=cvt8(s0,s1), AS1=cvt8(s2,s3);
    bf16x8 AD0=cvt8(d0,d1), AD1=cvt8(d2,d3);
    #pragma unroll
    for (int nt=0;nt<4;nt++){
      f32x4 am = {0.f,0.f,0.f,0.f};
      am = MFMA(AE0, wl[(    nt)*64+lane], am);
      am = MFMA(AE1, wl[( 4+ nt)*64+lane], am);
      am = MFMA(AS0, wl[( 8+ nt)*64+lane], am);
      am = MFMA(AS1, wl[(12+ nt)*64+lane], am);
      am = MFMA(AD0, wl[(16+ nt)*64+lane], am);
      am = MFMA(AD1, wl[(20+ nt)*64+lane], am);
      int col = c + 16*nt;
      #pragma unroll
      for (int e=0;e<4;e++)
        m16[(base+4*g+e)*64 + col] = (__bf16)(am[e] + bias[nt]);
    }
  }
}

// ---- phaseB: node-major over contiguous CSR rows. sigma=sigmoid(m16),
// gather Bh[src] (L3-hot), per-lane column sums -> h -> x_pre; both BN stats.
__global__ __launch_bounds__(256) void phaseB(
    const __bf16* __restrict__ m16, const int4* __restrict__ pairs,
    const float* __restrict__ Bh, const int* __restrict__ rowp,
    float* __restrict__ A_src,          // in/out -> x_pre
    float* __restrict__ est, float* __restrict__ nst, int Nn)
{
  __shared__ float sst[256];
  sst[threadIdx.x] = 0.f;
  __syncthreads();
  int lane = threadIdx.x & 63, w = threadIdx.x>>6;
  int chunk = (Nn + gridDim.x - 1)/gridDim.x;
  int n0 = blockIdx.x*chunk;
  int n1 = n0 + chunk; if (n1 > Nn) n1 = Nn;
  float e1=0.f, e2=0.f, p1=0.f, p2=0.f;
  for (int n=n0+w; n<n1; n+=4){
    int r0 = rowp[n], r1 = rowp[n+1];
    float ssum=0.f, bsum=0.f;
    for (int r=r0; r<r1; ++r){
      float mv = (float)m16[(long)r*64 + lane];
      int s = pairs[r].y;
      float bh = Bh[(long)s*64 + lane];
      float sg = 1.f/(1.f+__expf(-mv));
      ssum += sg; bsum += bh*sg;
      e1 += mv; e2 += mv*mv;
    }
    long xi = (long)n*64 + lane;
    float xp = A_src[xi] + bsum/(ssum+1e-6f);
    A_src[xi] = xp;
    p1 += xp; p2 += xp*xp;
  }
  atomicAdd(&sst[lane],     e1);
  atomicAdd(&sst[64+lane],  e2);
  atomicAdd(&sst[128+lane], p1);
  atomicAdd(&sst[192+lane], p2);
  __syncthreads();
  int t = threadIdx.x;
  if (t < 128) atomicAdd(&est[t], sst[t]);
  else         atomicAdd(&nst[t-128], sst[t]);
}

// x = nf + silu(bn(x_pre))
__global__ __launch_bounds__(256) void node_final(
    const float* __restrict__ nf, const float* __restrict__ xpre,
    const float* __restrict__ nst, const float* __restrict__ gam,
    const float* __restrict__ bet, float* __restrict__ xo, int Nn)
{
  long tid = blockIdx.x*blockDim.x + threadIdx.x;
  long stride = (long)gridDim.x*blockDim.x;
  int col = (int)(tid & 63);
  float invN = 1.f/(float)Nn;
  float mu = nst[col]*invN;
  float var = nst[64+col]*invN - mu*mu;
  float rs = rsqrtf(var + 1e-5f);
  float aa = gam[col]*rs;
  float bb = bet[col] - mu*aa;
  long total = (long)Nn*64;
  for (long i=tid; i<total; i+=stride){
    float z = xpre[i]*aa + bb;
    xo[i] = nf[i] + z/(1.f+__expf(-z));
  }
}

// y[eid] = ef[eid] + silu(bn(m16[pos])) — pure streaming, 8 threads per edge-row
__global__ __launch_bounds__(256) void edge_final(
    const __bf16* __restrict__ m16, const int4* __restrict__ pairs,
    const float* __restrict__ ef, const float* __restrict__ est,
    const float* __restrict__ gam, const float* __restrict__ bet,
    float* __restrict__ y, float invE, long E)
{
  int oct = threadIdx.x & 7;
  float aa[8], bb[8];
  #pragma unroll
  for (int j=0;j<8;j++){
    int col = oct*8 + j;
    float mu = est[col]*invE;
    float var = est[64+col]*invE - mu*mu;
    float rs = rsqrtf(var + 1e-5f);
    float ga = gam[col]*rs;
    aa[j] = ga; bb[j] = bet[col] - mu*ga;
  }
  long tid = (long)blockIdx.x*256 + threadIdx.x;
  long pstep = ((long)gridDim.x*256) >> 3;
  for (long p = tid>>3; p < E; p += pstep){
    int eid = pairs[p].x;
    bf16x8 mv = *(const bf16x8*)&m16[p*64 + oct*8];
    const float* rp = ef + (long)eid*64 + oct*8;
    float4 f0 = *(const float4*)rp, f1 = *(const float4*)(rp+4);
    float o[8];
    #pragma unroll
    for (int j=0;j<8;j++){
      float z = aa[j]*(float)mv[j] + bb[j];
      float ev = (j<4) ? ((const float*)&f0)[j] : ((const float*)&f1)[j-4];
      o[j] = ev + z/(1.f+__expf(-z));
    }
    float* yp = y + (long)eid*64 + oct*8;
    *(float4*)yp     = make_float4(o[0],o[1],o[2],o[3]);
    *(float4*)(yp+4) = make_float4(o[4],o[5],o[6],o[7]);
  }
}

extern "C" void kernel_launch(void* const* d_in, const int* in_sizes, int n_in,
                              void* d_out, int out_size, void* d_ws, size_t ws_size,
                              hipStream_t stream){
  const float* nf  = (const float*)d_in[0];
  const float* ef  = (const float*)d_in[1];
  const int*   src = (const int*)d_in[2];
  const int*   dst = (const int*)d_in[3];
  const float* W_sg=(const float*)d_in[4];  const float* b_sg=(const float*)d_in[5];
  const float* W_dg=(const float*)d_in[6];  const float* b_dg=(const float*)d_in[7];
  const float* W_eg=(const float*)d_in[8];  const float* b_eg=(const float*)d_in[9];
  const float* W_su=(const float*)d_in[10]; const float* b_su=(const float*)d_in[11];
  const float* W_du=(const float*)d_in[12]; const float* b_du=(const float*)d_in[13];
  const float* gn=(const float*)d_in[14];   const float* btn=(const float*)d_in[15];
  const float* ge=(const float*)d_in[16];   const float* bte=(const float*)d_in[17];

  int Nn = in_sizes[0]/64;
  int Ee = in_sizes[2];
  size_t Nf = (size_t)Nn*64;
  size_t Es = (size_t)Ee;

  float* ws    = (float*)d_ws;
  float* A_src = ws;                         // Nf (becomes x_pre)
  float* Bh    = ws + Nf;                    // Nf
  __bf16* m16  = (__bf16*)(ws + 2*Nf);       // Ee*64 bf16 = 32*Ee floats
  int4*  pairs = (int4*)(ws + 2*Nf + 32*Es); // Ee int4 = 4*Ee ints
  int*   cnt   = (int*)(pairs + Es);         // Nn
  int*   cnt2  = cnt + Nn;                   // Nn
  float* est   = (float*)(cnt2 + Nn);        // 128
  float* nst   = est + 128;                  // 128
  int*   rowp  = (int*)(nst + 128);          // Nn+1
  size_t woff  = 2*Nf + 32*Es + 4*Es + 2*(size_t)Nn + 256 + (size_t)Nn + 1;
  woff = (woff + 3) & ~(size_t)3;
  bf16x8* Wp   = (bf16x8*)(ws + woff);       // 2560 frags

  float* xo = (float*)d_out;
  float* yo = xo + Nf;

  // zero: cnt, cnt2, est, nst (contiguous)
  hipMemsetAsync(cnt, 0, (2*(size_t)Nn + 256)*sizeof(int), stream);

  wcvt<<<10,256,0,stream>>>(W_sg,W_dg,W_eg,W_su,W_du,Wp);

  int ntn = Nn/16;
  node_xform<<<(ntn+3)/4,256,0,stream>>>(nf,Wp,b_su,b_du,A_src,Bh,ntn);
  hist_k<<<2048,256,0,stream>>>(dst,cnt,Ee);
  scan_k<<<1,1024,0,stream>>>(cnt,rowp,Nn);
  fill_k<<<2048,256,0,stream>>>(src,dst,rowp,cnt2,pairs,Ee);
  int nte = Ee/16;
  phaseA<<<4096,256,0,stream>>>(ef,nf,pairs,b_sg,b_dg,b_eg,Wp,m16,nte);
  phaseB<<<2048,256,0,stream>>>(m16,pairs,Bh,rowp,A_src,est,nst,Nn);
  node_final<<<2048,256,0,stream>>>(nf,A_src,nst,gn,btn,xo,Nn);
  edge_final<<<2048,256,0,stream>>>(m16,pairs,ef,est,ge,bte,yo,
                                    1.f/(float)Ee,(long)Ee);
}

// Round 7
// 990.382 us; speedup vs baseline: 2.6987x; 1.0522x over previous
//
#include <hip/hip_runtime.h>
#include <hip/hip_bf16.h>

typedef __attribute__((ext_vector_type(8))) __bf16 bf16x8;
typedef __attribute__((ext_vector_type(4))) float f32x4;

#define MFMA(a,b,c) __builtin_amdgcn_mfma_f32_16x16x32_bf16((a),(b),(c),0,0,0)

__device__ __forceinline__ bf16x8 cvt8(float4 a, float4 b){
  bf16x8 r;
  r[0]=(__bf16)a.x; r[1]=(__bf16)a.y; r[2]=(__bf16)a.z; r[3]=(__bf16)a.w;
  r[4]=(__bf16)b.x; r[5]=(__bf16)b.y; r[6]=(__bf16)b.z; r[7]=(__bf16)b.w;
  return r;
}

// Pack 5 weight matrices [64][64] f32 into bf16 MFMA B-fragments.
// mats 0:sg 1:dg 2:eg 3:su 4:du; Wp[(m*8+kt*4+nt)*64+lane]:
// lane holds W[k=kt*32+(l>>4)*8+j][n=nt*16+(l&15)]
__global__ void wcvt(const float* __restrict__ W0, const float* __restrict__ W1,
                     const float* __restrict__ W2, const float* __restrict__ W3,
                     const float* __restrict__ W4, bf16x8* __restrict__ Wp){
  int tid = blockIdx.x*256 + threadIdx.x;
  if (tid >= 5*8*64) return;
  int lane = tid & 63, frag = (tid>>6)&7, m = tid>>9;
  const float* Ws[5] = {W0,W1,W2,W3,W4};
  const float* W = Ws[m];
  int kt = frag>>2, nt = frag&3, g = lane>>4, c = lane&15;
  bf16x8 v;
  #pragma unroll
  for (int j=0;j<8;j++) v[j] = (__bf16)W[(kt*32+g*8+j)*64 + nt*16 + c];
  Wp[tid] = v;
}

// 2 node transforms: A_src = nf@W_su+b_su, Bh = nf@W_du+b_du
__global__ __launch_bounds__(256) void node_xform(
    const float* __restrict__ nf, const bf16x8* __restrict__ Wp,
    const float* __restrict__ b_su, const float* __restrict__ b_du,
    float* __restrict__ A_src, float* __restrict__ Bh, int ntiles)
{
  int lane = threadIdx.x & 63;
  int gw = blockIdx.x*4 + (threadIdx.x>>6);
  if (gw >= ntiles) return;
  int g = lane>>4, c = lane&15;
  long base = (long)gw*16;
  const float* rp = nf + (base + c)*64 + g*8;
  float4 a0 = *(const float4*)rp,      a1 = *(const float4*)(rp+4);
  float4 a2 = *(const float4*)(rp+32), a3 = *(const float4*)(rp+36);
  bf16x8 A0 = cvt8(a0,a1), A1 = cvt8(a2,a3);
  const float* biases[2] = {b_su,b_du};
  float* outs[2] = {A_src,Bh};
  const int mats[2] = {3,4};
  #pragma unroll
  for (int i=0;i<2;i++){
    #pragma unroll
    for (int nt=0;nt<4;nt++){
      f32x4 acc = {0.f,0.f,0.f,0.f};
      acc = MFMA(A0, Wp[(mats[i]*8+nt)*64+lane],   acc);
      acc = MFMA(A1, Wp[(mats[i]*8+4+nt)*64+lane], acc);
      int col = c + nt*16;
      float bb = biases[i][col];
      #pragma unroll
      for (int e=0;e<4;e++) outs[i][(base+4*g+e)*64 + col] = acc[e] + bb;
    }
  }
}

// ---- CSR build on dst ----
__global__ void hist_k(const int* __restrict__ dst, int* __restrict__ cnt, int E){
  int i = blockIdx.x*256 + threadIdx.x, st = gridDim.x*256;
  for (; i<E; i+=st) atomicAdd(&cnt[dst[i]], 1);
}

__global__ __launch_bounds__(1024) void scan_k(const int* __restrict__ cnt,
                                               int* __restrict__ row, int Nn){
  __shared__ int part[1024];
  int t = threadIdx.x;
  int C = (Nn + 1023) >> 10;
  int lo = t*C;
  int hi = lo + C; if (hi > Nn) hi = Nn;
  int s = 0;
  for (int i=lo; i<hi; i++) s += cnt[i];
  part[t] = s;
  __syncthreads();
  for (int off=1; off<1024; off<<=1){
    int v = part[t];
    int u = (t>=off) ? part[t-off] : 0;
    __syncthreads();
    part[t] = v + u;
    __syncthreads();
  }
  int excl = (t==0) ? 0 : part[t-1];
  for (int i=lo; i<hi; i++){ row[i] = excl; excl += cnt[i]; }
  if (t==1023) row[Nn] = excl;
}

// fill CSR-position records: {edge_id, src}; cnt2 is the cursor (rowp kept clean)
__global__ void fill_k(const int* __restrict__ src, const int* __restrict__ dst,
                       const int* __restrict__ rowp, int* __restrict__ cnt2,
                       int2* __restrict__ pairs, int E){
  int i = blockIdx.x*256 + threadIdx.x, st = gridDim.x*256;
  for (; i<E; i+=st){
    int d = dst[i];
    int pos = rowp[d] + atomicAdd(&cnt2[d], 1);
    pairs[pos] = make_int2(i, src[i]);
  }
}

// ---- phaseA: eid-major. m[eid] = ef[eid]@W_eg + nf[src]@W_sg + nf[dst]@W_dg
// + biases, stored bf16 in EID order. ef read + m16 write fully streaming;
// only nf gathers (L2/L3-hot). No atomics, no shfl, no index array.
__global__ __launch_bounds__(256) void phaseA(
    const float* __restrict__ ef, const float* __restrict__ nf,
    const int* __restrict__ src, const int* __restrict__ dst,
    const float* __restrict__ b_sg, const float* __restrict__ b_dg,
    const float* __restrict__ b_eg,
    const bf16x8* __restrict__ Wp,
    __bf16* __restrict__ m16, int ntiles)
{
  __shared__ bf16x8 wl[24*64];   // 0-7: eg, 8-15: sg, 16-23: dg
  {
    int t = threadIdx.x;
    #pragma unroll
    for (int i=0;i<6;i++){
      int idx = i*256 + t, fr = idx>>6, ln = idx&63;
      int mat = (fr<8) ? 2 : ((fr<16) ? 0 : 1);
      wl[idx] = Wp[(mat*8 + (fr&7))*64 + ln];
    }
  }
  __syncthreads();
  int lane = threadIdx.x & 63, g = lane>>4, c = lane&15;
  int gw = blockIdx.x*4 + (threadIdx.x>>6);
  int nw = gridDim.x*4;
  float bias[4];
  #pragma unroll
  for (int nt=0;nt<4;nt++){
    int col = c + 16*nt;
    bias[nt] = b_sg[col] + b_dg[col] + b_eg[col];
  }
  for (int tt=gw; tt<ntiles; tt+=nw){
    long base = (long)tt*16;
    int s_c = src[base+c], d_c = dst[base+c];
    const float* rpe = ef + (base+c)*64 + g*8;
    const float* rps = nf + (long)s_c*64 + g*8;
    const float* rpd = nf + (long)d_c*64 + g*8;
    float4 e0=*(const float4*)rpe,      e1=*(const float4*)(rpe+4);
    float4 e2=*(const float4*)(rpe+32), e3=*(const float4*)(rpe+36);
    float4 s0=*(const float4*)rps,      s1=*(const float4*)(rps+4);
    float4 s2=*(const float4*)(rps+32), s3=*(const float4*)(rps+36);
    float4 d0=*(const float4*)rpd,      d1=*(const float4*)(rpd+4);
    float4 d2=*(const float4*)(rpd+32), d3=*(const float4*)(rpd+36);
    bf16x8 AE0=cvt8(e0,e1), AE1=cvt8(e2,e3);
    bf16x8 AS0=cvt8(s0,s1), AS1=cvt8(s2,s3);
    bf16x8 AD0=cvt8(d0,d1), AD1=cvt8(d2,d3);
    #pragma unroll
    for (int nt=0;nt<4;nt++){
      f32x4 am = {0.f,0.f,0.f,0.f};
      am = MFMA(AE0, wl[(    nt)*64+lane], am);
      am = MFMA(AE1, wl[( 4+ nt)*64+lane], am);
      am = MFMA(AS0, wl[( 8+ nt)*64+lane], am);
      am = MFMA(AS1, wl[(12+ nt)*64+lane], am);
      am = MFMA(AD0, wl[(16+ nt)*64+lane], am);
      am = MFMA(AD1, wl[(20+ nt)*64+lane], am);
      int col = c + 16*nt;
      #pragma unroll
      for (int e=0;e<4;e++)
        m16[(base+4*g+e)*64 + col] = (__bf16)(am[e] + bias[nt]);
    }
  }
}

// ---- phaseB: node-major over CSR rows. Gather m16[eid] + Bh[src] rows,
// sigma=sigmoid(m), column sums -> h -> x_pre; BOTH BN stat sets.
// 2-edge manual unroll for load ILP.
__global__ __launch_bounds__(256) void phaseB(
    const __bf16* __restrict__ m16, const int2* __restrict__ pairs,
    const float* __restrict__ Bh, const int* __restrict__ rowp,
    float* __restrict__ A_src,          // in/out -> x_pre
    float* __restrict__ est, float* __restrict__ nst, int Nn)
{
  __shared__ float sst[256];
  sst[threadIdx.x] = 0.f;
  __syncthreads();
  int lane = threadIdx.x & 63, w = threadIdx.x>>6;
  int chunk = (Nn + gridDim.x - 1)/gridDim.x;
  int n0 = blockIdx.x*chunk;
  int n1 = n0 + chunk; if (n1 > Nn) n1 = Nn;
  float e1=0.f, e2=0.f, p1=0.f, p2=0.f;
  for (int n=n0+w; n<n1; n+=4){
    int r0 = rowp[n], r1 = rowp[n+1];
    float ssum=0.f, bsum=0.f;
    int r = r0;
    for (; r+2 <= r1; r+=2){
      int2 q0 = pairs[r], q1 = pairs[r+1];
      float mv0 = (float)m16[(long)q0.x*64 + lane];
      float bh0 = Bh[(long)q0.y*64 + lane];
      float mv1 = (float)m16[(long)q1.x*64 + lane];
      float bh1 = Bh[(long)q1.y*64 + lane];
      float sg0 = 1.f/(1.f+__expf(-mv0));
      float sg1 = 1.f/(1.f+__expf(-mv1));
      ssum += sg0 + sg1; bsum += bh0*sg0 + bh1*sg1;
      e1 += mv0 + mv1;   e2 += mv0*mv0 + mv1*mv1;
    }
    if (r < r1){
      int2 q0 = pairs[r];
      float mv0 = (float)m16[(long)q0.x*64 + lane];
      float bh0 = Bh[(long)q0.y*64 + lane];
      float sg0 = 1.f/(1.f+__expf(-mv0));
      ssum += sg0; bsum += bh0*sg0;
      e1 += mv0;   e2 += mv0*mv0;
    }
    long xi = (long)n*64 + lane;
    float xp = A_src[xi] + bsum/(ssum+1e-6f);
    A_src[xi] = xp;
    p1 += xp; p2 += xp*xp;
  }
  atomicAdd(&sst[lane],     e1);
  atomicAdd(&sst[64+lane],  e2);
  atomicAdd(&sst[128+lane], p1);
  atomicAdd(&sst[192+lane], p2);
  __syncthreads();
  int t = threadIdx.x;
  if (t < 128) atomicAdd(&est[t], sst[t]);
  else         atomicAdd(&nst[t-128], sst[t]);
}

// x = nf + silu(bn(x_pre))
__global__ __launch_bounds__(256) void node_final(
    const float* __restrict__ nf, const float* __restrict__ xpre,
    const float* __restrict__ nst, const float* __restrict__ gam,
    const float* __restrict__ bet, float* __restrict__ xo, int Nn)
{
  long tid = blockIdx.x*blockDim.x + threadIdx.x;
  long stride = (long)gridDim.x*blockDim.x;
  int col = (int)(tid & 63);
  float invN = 1.f/(float)Nn;
  float mu = nst[col]*invN;
  float var = nst[64+col]*invN - mu*mu;
  float rs = rsqrtf(var + 1e-5f);
  float aa = gam[col]*rs;
  float bb = bet[col] - mu*aa;
  long total = (long)Nn*64;
  for (long i=tid; i<total; i+=stride){
    float z = xpre[i]*aa + bb;
    xo[i] = nf[i] + z/(1.f+__expf(-z));
  }
}

// y = ef + silu(bn(m16)) — everything in eid order: pure streaming.
__global__ __launch_bounds__(256) void edge_final(
    const __bf16* __restrict__ m16, const float* __restrict__ ef,
    const float* __restrict__ est, const float* __restrict__ gam,
    const float* __restrict__ bet, float* __restrict__ y, float invE, long E)
{
  int oct = threadIdx.x & 7;
  float aa[8], bb[8];
  #pragma unroll
  for (int j=0;j<8;j++){
    int col = oct*8 + j;
    float mu = est[col]*invE;
    float var = est[64+col]*invE - mu*mu;
    float rs = rsqrtf(var + 1e-5f);
    float ga = gam[col]*rs;
    aa[j] = ga; bb[j] = bet[col] - mu*ga;
  }
  long tid = (long)blockIdx.x*256 + threadIdx.x;
  long pstep = ((long)gridDim.x*256) >> 3;
  for (long p = tid>>3; p < E; p += pstep){
    bf16x8 mv = *(const bf16x8*)&m16[p*64 + oct*8];
    const float* rp = ef + p*64 + oct*8;
    float4 f0 = *(const float4*)rp, f1 = *(const float4*)(rp+4);
    float o[8];
    #pragma unroll
    for (int j=0;j<8;j++){
      float z = aa[j]*(float)mv[j] + bb[j];
      float ev = (j<4) ? ((const float*)&f0)[j] : ((const float*)&f1)[j-4];
      o[j] = ev + z/(1.f+__expf(-z));
    }
    float* yp = y + p*64 + oct*8;
    *(float4*)yp     = make_float4(o[0],o[1],o[2],o[3]);
    *(float4*)(yp+4) = make_float4(o[4],o[5],o[6],o[7]);
  }
}

extern "C" void kernel_launch(void* const* d_in, const int* in_sizes, int n_in,
                              void* d_out, int out_size, void* d_ws, size_t ws_size,
                              hipStream_t stream){
  const float* nf  = (const float*)d_in[0];
  const float* ef  = (const float*)d_in[1];
  const int*   src = (const int*)d_in[2];
  const int*   dst = (const int*)d_in[3];
  const float* W_sg=(const float*)d_in[4];  const float* b_sg=(const float*)d_in[5];
  const float* W_dg=(const float*)d_in[6];  const float* b_dg=(const float*)d_in[7];
  const float* W_eg=(const float*)d_in[8];  const float* b_eg=(const float*)d_in[9];
  const float* W_su=(const float*)d_in[10]; const float* b_su=(const float*)d_in[11];
  const float* W_du=(const float*)d_in[12]; const float* b_du=(const float*)d_in[13];
  const float* gn=(const float*)d_in[14];   const float* btn=(const float*)d_in[15];
  const float* ge=(const float*)d_in[16];   const float* bte=(const float*)d_in[17];

  int Nn = in_sizes[0]/64;
  int Ee = in_sizes[2];
  size_t Nf = (size_t)Nn*64;
  size_t Es = (size_t)Ee;

  float* ws    = (float*)d_ws;
  float* A_src = ws;                          // Nf (becomes x_pre)
  float* Bh    = ws + Nf;                     // Nf
  __bf16* m16  = (__bf16*)(ws + 2*Nf);        // Ee*64 bf16 = 32*Es floats
  int2*  pairs = (int2*)(ws + 2*Nf + 32*Es);  // Es int2 = 2*Es floats
  int*   cnt   = (int*)(pairs + Es);          // Nn
  int*   cnt2  = cnt + Nn;                    // Nn
  float* est   = (float*)(cnt2 + Nn);         // 128
  float* nst   = est + 128;                   // 128
  int*   rowp  = (int*)(nst + 128);           // Nn+1
  size_t woff  = 2*Nf + 32*Es + 2*Es + 2*(size_t)Nn + 256 + (size_t)Nn + 1;
  woff = (woff + 15) & ~(size_t)15;
  bf16x8* Wp   = (bf16x8*)(ws + woff);        // 2560 frags

  float* xo = (float*)d_out;
  float* yo = xo + Nf;

  // zero: cnt, cnt2, est, nst (contiguous)
  hipMemsetAsync(cnt, 0, (2*(size_t)Nn + 256)*sizeof(int), stream);

  wcvt<<<10,256,0,stream>>>(W_sg,W_dg,W_eg,W_su,W_du,Wp);

  int ntn = Nn/16;
  node_xform<<<(ntn+3)/4,256,0,stream>>>(nf,Wp,b_su,b_du,A_src,Bh,ntn);
  hist_k<<<2048,256,0,stream>>>(dst,cnt,Ee);
  scan_k<<<1,1024,0,stream>>>(cnt,rowp,Nn);
  fill_k<<<2048,256,0,stream>>>(src,dst,rowp,cnt2,pairs,Ee);
  int nte = Ee/16;
  phaseA<<<4096,256,0,stream>>>(ef,nf,src,dst,b_sg,b_dg,b_eg,Wp,m16,nte);
  phaseB<<<2048,256,0,stream>>>(m16,pairs,Bh,rowp,A_src,est,nst,Nn);
  node_final<<<2048,256,0,stream>>>(nf,A_src,nst,gn,btn,xo,Nn);
  edge_final<<<2048,256,0,stream>>>(m16,ef,est,ge,bte,yo,
                                    1.f/(float)Ee,(long)Ee);
}

// Round 8
// 935.577 us; speedup vs baseline: 2.8568x; 1.0586x over previous
//
#include <hip/hip_runtime.h>
#include <hip/hip_bf16.h>

typedef __attribute__((ext_vector_type(8))) __bf16 bf16x8;
typedef __attribute__((ext_vector_type(4))) float f32x4;

#define MFMA(a,b,c) __builtin_amdgcn_mfma_f32_16x16x32_bf16((a),(b),(c),0,0,0)

__device__ __forceinline__ bf16x8 cvt8(float4 a, float4 b){
  bf16x8 r;
  r[0]=(__bf16)a.x; r[1]=(__bf16)a.y; r[2]=(__bf16)a.z; r[3]=(__bf16)a.w;
  r[4]=(__bf16)b.x; r[5]=(__bf16)b.y; r[6]=(__bf16)b.z; r[7]=(__bf16)b.w;
  return r;
}

// Pack 5 weight matrices [64][64] f32 into bf16 MFMA B-fragments.
// mats 0:sg 1:dg 2:eg 3:su 4:du; Wp[(m*8+kt*4+nt)*64+lane]:
// lane holds W[k=kt*32+(l>>4)*8+j][n=nt*16+(l&15)]
__global__ void wcvt(const float* __restrict__ W0, const float* __restrict__ W1,
                     const float* __restrict__ W2, const float* __restrict__ W3,
                     const float* __restrict__ W4, bf16x8* __restrict__ Wp){
  int tid = blockIdx.x*256 + threadIdx.x;
  if (tid >= 5*8*64) return;
  int lane = tid & 63, frag = (tid>>6)&7, m = tid>>9;
  const float* Ws[5] = {W0,W1,W2,W3,W4};
  const float* W = Ws[m];
  int kt = frag>>2, nt = frag&3, g = lane>>4, c = lane&15;
  bf16x8 v;
  #pragma unroll
  for (int j=0;j<8;j++) v[j] = (__bf16)W[(kt*32+g*8+j)*64 + nt*16 + c];
  Wp[tid] = v;
}

// 2 node transforms: A_src = nf@W_su+b_su, Bh = nf@W_du+b_du
__global__ __launch_bounds__(256) void node_xform(
    const float* __restrict__ nf, const bf16x8* __restrict__ Wp,
    const float* __restrict__ b_su, const float* __restrict__ b_du,
    float* __restrict__ A_src, float* __restrict__ Bh, int ntiles)
{
  int lane = threadIdx.x & 63;
  int gw = blockIdx.x*4 + (threadIdx.x>>6);
  if (gw >= ntiles) return;
  int g = lane>>4, c = lane&15;
  long base = (long)gw*16;
  const float* rp = nf + (base + c)*64 + g*8;
  float4 a0 = *(const float4*)rp,      a1 = *(const float4*)(rp+4);
  float4 a2 = *(const float4*)(rp+32), a3 = *(const float4*)(rp+36);
  bf16x8 A0 = cvt8(a0,a1), A1 = cvt8(a2,a3);
  const float* biases[2] = {b_su,b_du};
  float* outs[2] = {A_src,Bh};
  const int mats[2] = {3,4};
  #pragma unroll
  for (int i=0;i<2;i++){
    #pragma unroll
    for (int nt=0;nt<4;nt++){
      f32x4 acc = {0.f,0.f,0.f,0.f};
      acc = MFMA(A0, Wp[(mats[i]*8+nt)*64+lane],   acc);
      acc = MFMA(A1, Wp[(mats[i]*8+4+nt)*64+lane], acc);
      int col = c + nt*16;
      float bb = biases[i][col];
      #pragma unroll
      for (int e=0;e<4;e++) outs[i][(base+4*g+e)*64 + col] = acc[e] + bb;
    }
  }
}

// ---- CSR build on dst ----
__global__ void hist_k(const int* __restrict__ dst, int* __restrict__ cnt, int E){
  int i = blockIdx.x*256 + threadIdx.x, st = gridDim.x*256;
  for (; i<E; i+=st) atomicAdd(&cnt[dst[i]], 1);
}

__global__ __launch_bounds__(1024) void scan_k(const int* __restrict__ cnt,
                                               int* __restrict__ row, int Nn){
  __shared__ int part[1024];
  int t = threadIdx.x;
  int C = (Nn + 1023) >> 10;
  int lo = t*C;
  int hi = lo + C; if (hi > Nn) hi = Nn;
  int s = 0;
  for (int i=lo; i<hi; i++) s += cnt[i];
  part[t] = s;
  __syncthreads();
  for (int off=1; off<1024; off<<=1){
    int v = part[t];
    int u = (t>=off) ? part[t-off] : 0;
    __syncthreads();
    part[t] = v + u;
    __syncthreads();
  }
  int excl = (t==0) ? 0 : part[t-1];
  for (int i=lo; i<hi; i++){ row[i] = excl; excl += cnt[i]; }
  if (t==1023) row[Nn] = excl;
}

// fill CSR-position records: {edge_id, src}; cnt2 is the cursor (rowp kept clean)
__global__ void fill_k(const int* __restrict__ src, const int* __restrict__ dst,
                       const int* __restrict__ rowp, int* __restrict__ cnt2,
                       int2* __restrict__ pairs, int E){
  int i = blockIdx.x*256 + threadIdx.x, st = gridDim.x*256;
  for (; i<E; i+=st){
    int d = dst[i];
    int pos = rowp[d] + atomicAdd(&cnt2[d], 1);
    pairs[pos] = make_int2(i, src[i]);
  }
}

// ---- phaseA: eid-major, index loads pipelined one iteration ahead.
// m[eid] = ef[eid]@W_eg + nf[src]@W_sg + nf[dst]@W_dg + biases, stored bf16.
__global__ __launch_bounds__(256) void phaseA(
    const float* __restrict__ ef, const float* __restrict__ nf,
    const int* __restrict__ src, const int* __restrict__ dst,
    const float* __restrict__ b_sg, const float* __restrict__ b_dg,
    const float* __restrict__ b_eg,
    const bf16x8* __restrict__ Wp,
    __bf16* __restrict__ m16, int ntiles)
{
  __shared__ bf16x8 wl[24*64];   // 0-7: eg, 8-15: sg, 16-23: dg
  {
    int t = threadIdx.x;
    #pragma unroll
    for (int i=0;i<6;i++){
      int idx = i*256 + t, fr = idx>>6, ln = idx&63;
      int mat = (fr<8) ? 2 : ((fr<16) ? 0 : 1);
      wl[idx] = Wp[(mat*8 + (fr&7))*64 + ln];
    }
  }
  __syncthreads();
  int lane = threadIdx.x & 63, g = lane>>4, c = lane&15;
  int gw = blockIdx.x*4 + (threadIdx.x>>6);
  int nw = gridDim.x*4;
  float bias[4];
  #pragma unroll
  for (int nt=0;nt<4;nt++){
    int col = c + 16*nt;
    bias[nt] = b_sg[col] + b_dg[col] + b_eg[col];
  }
  int sc = 0, dc = 0;
  if (gw < ntiles){ sc = src[(long)gw*16 + c]; dc = dst[(long)gw*16 + c]; }
  for (int tt=gw; tt<ntiles; tt+=nw){
    long base = (long)tt*16;
    // prefetch next iteration's indices (overlaps with MFMA/store below)
    int tn = tt + nw;
    int sn = sc, dn = dc;
    if (tn < ntiles){ sn = src[(long)tn*16 + c]; dn = dst[(long)tn*16 + c]; }
    const float* rpe = ef + (base+c)*64 + g*8;
    const float* rps = nf + (long)sc*64 + g*8;
    const float* rpd = nf + (long)dc*64 + g*8;
    float4 e0=*(const float4*)rpe,      e1=*(const float4*)(rpe+4);
    float4 e2=*(const float4*)(rpe+32), e3=*(const float4*)(rpe+36);
    float4 s0=*(const float4*)rps,      s1=*(const float4*)(rps+4);
    float4 s2=*(const float4*)(rps+32), s3=*(const float4*)(rps+36);
    float4 d0=*(const float4*)rpd,      d1=*(const float4*)(rpd+4);
    float4 d2=*(const float4*)(rpd+32), d3=*(const float4*)(rpd+36);
    bf16x8 AE0=cvt8(e0,e1), AE1=cvt8(e2,e3);
    bf16x8 AS0=cvt8(s0,s1), AS1=cvt8(s2,s3);
    bf16x8 AD0=cvt8(d0,d1), AD1=cvt8(d2,d3);
    #pragma unroll
    for (int nt=0;nt<4;nt++){
      f32x4 am = {0.f,0.f,0.f,0.f};
      am = MFMA(AE0, wl[(    nt)*64+lane], am);
      am = MFMA(AE1, wl[( 4+ nt)*64+lane], am);
      am = MFMA(AS0, wl[( 8+ nt)*64+lane], am);
      am = MFMA(AS1, wl[(12+ nt)*64+lane], am);
      am = MFMA(AD0, wl[(16+ nt)*64+lane], am);
      am = MFMA(AD1, wl[(20+ nt)*64+lane], am);
      int col = c + 16*nt;
      #pragma unroll
      for (int e=0;e<4;e++)
        m16[(base+4*g+e)*64 + col] = (__bf16)(am[e] + bias[nt]);
    }
    sc = sn; dc = dn;
  }
}

// ---- phaseB: node-major over CSR rows. Gather m16[eid] + Bh[src] rows,
// sigma=sigmoid(m), column sums -> h -> x_pre; BOTH BN stat sets.
// 4-edge unroll: 8 independent loads in flight per wave.
__global__ __launch_bounds__(256) void phaseB(
    const __bf16* __restrict__ m16, const int2* __restrict__ pairs,
    const float* __restrict__ Bh, const int* __restrict__ rowp,
    float* __restrict__ A_src,          // in/out -> x_pre
    float* __restrict__ est, float* __restrict__ nst, int Nn)
{
  __shared__ float sst[256];
  sst[threadIdx.x] = 0.f;
  __syncthreads();
  int lane = threadIdx.x & 63, w = threadIdx.x>>6;
  int chunk = (Nn + gridDim.x - 1)/gridDim.x;
  int n0 = blockIdx.x*chunk;
  int n1 = n0 + chunk; if (n1 > Nn) n1 = Nn;
  float e1=0.f, e2=0.f, p1=0.f, p2=0.f;
  for (int n=n0+w; n<n1; n+=4){
    int r0 = rowp[n], r1 = rowp[n+1];
    float ssum=0.f, bsum=0.f;
    int r = r0;
    for (; r+4 <= r1; r+=4){
      int2 q0 = pairs[r],   q1 = pairs[r+1];
      int2 q2 = pairs[r+2], q3 = pairs[r+3];
      float mv0 = (float)m16[(long)q0.x*64 + lane];
      float mv1 = (float)m16[(long)q1.x*64 + lane];
      float mv2 = (float)m16[(long)q2.x*64 + lane];
      float mv3 = (float)m16[(long)q3.x*64 + lane];
      float bh0 = Bh[(long)q0.y*64 + lane];
      float bh1 = Bh[(long)q1.y*64 + lane];
      float bh2 = Bh[(long)q2.y*64 + lane];
      float bh3 = Bh[(long)q3.y*64 + lane];
      float sg0 = 1.f/(1.f+__expf(-mv0));
      float sg1 = 1.f/(1.f+__expf(-mv1));
      float sg2 = 1.f/(1.f+__expf(-mv2));
      float sg3 = 1.f/(1.f+__expf(-mv3));
      ssum += (sg0+sg1) + (sg2+sg3);
      bsum += (bh0*sg0 + bh1*sg1) + (bh2*sg2 + bh3*sg3);
      e1 += (mv0+mv1) + (mv2+mv3);
      e2 += (mv0*mv0 + mv1*mv1) + (mv2*mv2 + mv3*mv3);
    }
    for (; r < r1; ++r){
      int2 q0 = pairs[r];
      float mv0 = (float)m16[(long)q0.x*64 + lane];
      float bh0 = Bh[(long)q0.y*64 + lane];
      float sg0 = 1.f/(1.f+__expf(-mv0));
      ssum += sg0; bsum += bh0*sg0;
      e1 += mv0;   e2 += mv0*mv0;
    }
    long xi = (long)n*64 + lane;
    float xp = A_src[xi] + bsum/(ssum+1e-6f);
    A_src[xi] = xp;
    p1 += xp; p2 += xp*xp;
  }
  atomicAdd(&sst[lane],     e1);
  atomicAdd(&sst[64+lane],  e2);
  atomicAdd(&sst[128+lane], p1);
  atomicAdd(&sst[192+lane], p2);
  __syncthreads();
  int t = threadIdx.x;
  if (t < 128) atomicAdd(&est[t], sst[t]);
  else         atomicAdd(&nst[t-128], sst[t]);
}

// x = nf + silu(bn(x_pre))
__global__ __launch_bounds__(256) void node_final(
    const float* __restrict__ nf, const float* __restrict__ xpre,
    const float* __restrict__ nst, const float* __restrict__ gam,
    const float* __restrict__ bet, float* __restrict__ xo, int Nn)
{
  long tid = blockIdx.x*blockDim.x + threadIdx.x;
  long stride = (long)gridDim.x*blockDim.x;
  int col = (int)(tid & 63);
  float invN = 1.f/(float)Nn;
  float mu = nst[col]*invN;
  float var = nst[64+col]*invN - mu*mu;
  float rs = rsqrtf(var + 1e-5f);
  float aa = gam[col]*rs;
  float bb = bet[col] - mu*aa;
  long total = (long)Nn*64;
  for (long i=tid; i<total; i+=stride){
    float z = xpre[i]*aa + bb;
    xo[i] = nf[i] + z/(1.f+__expf(-z));
  }
}

// y = ef + silu(bn(m16)) — everything in eid order: pure streaming.
__global__ __launch_bounds__(256) void edge_final(
    const __bf16* __restrict__ m16, const float* __restrict__ ef,
    const float* __restrict__ est, const float* __restrict__ gam,
    const float* __restrict__ bet, float* __restrict__ y, float invE, long E)
{
  int oct = threadIdx.x & 7;
  float aa[8], bb[8];
  #pragma unroll
  for (int j=0;j<8;j++){
    int col = oct*8 + j;
    float mu = est[col]*invE;
    float var = est[64+col]*invE - mu*mu;
    float rs = rsqrtf(var + 1e-5f);
    float ga = gam[col]*rs;
    aa[j] = ga; bb[j] = bet[col] - mu*ga;
  }
  long tid = (long)blockIdx.x*256 + threadIdx.x;
  long pstep = ((long)gridDim.x*256) >> 3;
  for (long p = tid>>3; p < E; p += pstep){
    bf16x8 mv = *(const bf16x8*)&m16[p*64 + oct*8];
    const float* rp = ef + p*64 + oct*8;
    float4 f0 = *(const float4*)rp, f1 = *(const float4*)(rp+4);
    float o[8];
    #pragma unroll
    for (int j=0;j<8;j++){
      float z = aa[j]*(float)mv[j] + bb[j];
      float ev = (j<4) ? ((const float*)&f0)[j] : ((const float*)&f1)[j-4];
      o[j] = ev + z/(1.f+__expf(-z));
    }
    float* yp = y + p*64 + oct*8;
    *(float4*)yp     = make_float4(o[0],o[1],o[2],o[3]);
    *(float4*)(yp+4) = make_float4(o[4],o[5],o[6],o[7]);
  }
}

extern "C" void kernel_launch(void* const* d_in, const int* in_sizes, int n_in,
                              void* d_out, int out_size, void* d_ws, size_t ws_size,
                              hipStream_t stream){
  const float* nf  = (const float*)d_in[0];
  const float* ef  = (const float*)d_in[1];
  const int*   src = (const int*)d_in[2];
  const int*   dst = (const int*)d_in[3];
  const float* W_sg=(const float*)d_in[4];  const float* b_sg=(const float*)d_in[5];
  const float* W_dg=(const float*)d_in[6];  const float* b_dg=(const float*)d_in[7];
  const float* W_eg=(const float*)d_in[8];  const float* b_eg=(const float*)d_in[9];
  const float* W_su=(const float*)d_in[10]; const float* b_su=(const float*)d_in[11];
  const float* W_du=(const float*)d_in[12]; const float* b_du=(const float*)d_in[13];
  const float* gn=(const float*)d_in[14];   const float* btn=(const float*)d_in[15];
  const float* ge=(const float*)d_in[16];   const float* bte=(const float*)d_in[17];

  int Nn = in_sizes[0]/64;
  int Ee = in_sizes[2];
  size_t Nf = (size_t)Nn*64;
  size_t Es = (size_t)Ee;

  float* ws    = (float*)d_ws;
  float* A_src = ws;                          // Nf (becomes x_pre)
  float* Bh    = ws + Nf;                     // Nf
  __bf16* m16  = (__bf16*)(ws + 2*Nf);        // Ee*64 bf16 = 32*Es floats
  int2*  pairs = (int2*)(ws + 2*Nf + 32*Es);  // Es int2 = 2*Es floats
  int*   cnt   = (int*)(pairs + Es);          // Nn
  int*   cnt2  = cnt + Nn;                    // Nn
  float* est   = (float*)(cnt2 + Nn);         // 128
  float* nst   = est + 128;                   // 128
  int*   rowp  = (int*)(nst + 128);           // Nn+1
  size_t woff  = 2*Nf + 32*Es + 2*Es + 2*(size_t)Nn + 256 + (size_t)Nn + 1;
  woff = (woff + 15) & ~(size_t)15;
  bf16x8* Wp   = (bf16x8*)(ws + woff);        // 2560 frags

  float* xo = (float*)d_out;
  float* yo = xo + Nf;

  // zero: cnt, cnt2, est, nst (contiguous)
  hipMemsetAsync(cnt, 0, (2*(size_t)Nn + 256)*sizeof(int), stream);

  wcvt<<<10,256,0,stream>>>(W_sg,W_dg,W_eg,W_su,W_du,Wp);

  int ntn = Nn/16;
  node_xform<<<(ntn+3)/4,256,0,stream>>>(nf,Wp,b_su,b_du,A_src,Bh,ntn);
  hist_k<<<2048,256,0,stream>>>(dst,cnt,Ee);
  scan_k<<<1,1024,0,stream>>>(cnt,rowp,Nn);
  fill_k<<<2048,256,0,stream>>>(src,dst,rowp,cnt2,pairs,Ee);
  int nte = Ee/16;
  phaseA<<<4096,256,0,stream>>>(ef,nf,src,dst,b_sg,b_dg,b_eg,Wp,m16,nte);
  phaseB<<<4096,256,0,stream>>>(m16,pairs,Bh,rowp,A_src,est,nst,Nn);
  node_final<<<2048,256,0,stream>>>(nf,A_src,nst,gn,btn,xo,Nn);
  edge_final<<<2048,256,0,stream>>>(m16,ef,est,ge,bte,yo,
                                    1.f/(float)Ee,(long)Ee);
}